// Round 1
// baseline (359.295 us; speedup 1.0000x reference)
//
#include <hip/hip_runtime.h>
#include <stddef.h>

// Additive attention: out = softmax_k(mask(sum_h wv_h * tanh(qW_h + kW_h))) @ V
// tanh(q+k) = 1 - 2/(1 + e^{2q} e^{2k})  -> precompute Eq=e^{2q}, Ek=e^{2k};
// score = W0 + sum_h wv2_h * rcp(1 + Eq_h*Ek_h), wv2 = -2*wv, W0 = sum_h wv_h.

__device__ __forceinline__ float fast_rcp(float x)  { return __builtin_amdgcn_rcpf(x); }
__device__ __forceinline__ float fast_exp2(float x) { return __builtin_amdgcn_exp2f(x); }

#define C2F 2.88539008177792681f   // 2*log2(e)
#define L2E 1.44269504088896340f   // log2(e)

// ---------------------------------------------------------------------------
// Projection: P = in[rows x 256] @ W[256 x 64], out = exp2(C2F * P)
// TRANSPOSED (keys): out = EkT[((b*16 + (k>>7))*64 + h)*128 + (k&127)]
// else (queries):    out = Eq[(b*rowsPerB + row)*64 + h]
// Block: 256 threads, 64 rows. j=t>>4 (h-quad), g=t&15 (row), rows r=g+16m.
// ---------------------------------------------------------------------------
template<bool TRANSPOSED>
__global__ __launch_bounds__(256)
void proj_kernel(const float* __restrict__ in, const float* __restrict__ W,
                 float* __restrict__ out, const int* __restrict__ vlens,
                 int rowsPerB)
{
  const int t  = threadIdx.x;
  const int b  = blockIdx.x & 15;
  const int rt = blockIdx.x >> 4;
  const int r0 = rt * 64;
  if constexpr (TRANSPOSED) {
    if (r0 >= vlens[b]) return;   // whole block invalid (uniform early exit)
  }

  __shared__ float4 Wlds[256 * 16];   // [d][h-quad]
  __shared__ float  klds[64 * 36];    // [row][d-chunk], padded to 36

  // stage W (64KB) cooperatively
  const float4* W4 = (const float4*)W;
  #pragma unroll
  for (int i = 0; i < 16; ++i) Wlds[t + 256 * i] = W4[t + 256 * i];

  const float* inb = in + ((size_t)b * rowsPerB + r0) * 256;
  const int j = t >> 4;
  const int g = t & 15;

  float acc[4][4];
  #pragma unroll
  for (int m = 0; m < 4; ++m)
    acc[m][0] = acc[m][1] = acc[m][2] = acc[m][3] = 0.f;

  for (int dc = 0; dc < 8; ++dc) {
    { // stage 64x32 chunk of input rows
      const int row = t >> 2, cs = (t & 3) * 8;
      const float* s = inb + row * 256 + dc * 32 + cs;
      float4 a0 = *(const float4*)s;
      float4 a1 = *(const float4*)(s + 4);
      float* dst = &klds[row * 36 + cs];
      *(float4*)dst       = a0;
      *(float4*)(dst + 4) = a1;
    }
    __syncthreads();
    #pragma unroll
    for (int d = 0; d < 32; ++d) {
      float4 w4 = Wlds[(dc * 32 + d) * 16 + j];
      #pragma unroll
      for (int m = 0; m < 4; ++m) {
        float kv = klds[(g + 16 * m) * 36 + d];
        acc[m][0] = fmaf(kv, w4.x, acc[m][0]);
        acc[m][1] = fmaf(kv, w4.y, acc[m][1]);
        acc[m][2] = fmaf(kv, w4.z, acc[m][2]);
        acc[m][3] = fmaf(kv, w4.w, acc[m][3]);
      }
    }
    __syncthreads();
  }

  if constexpr (TRANSPOSED) {
    #pragma unroll
    for (int m = 0; m < 4; ++m) {
      int k = r0 + g + 16 * m;
      size_t base = ((size_t)(b * 16 + (k >> 7)) * 64) * 128 + (k & 127);
      #pragma unroll
      for (int i = 0; i < 4; ++i)
        out[base + (size_t)(4 * j + i) * 128] = fast_exp2(C2F * acc[m][i]);
    }
  } else {
    #pragma unroll
    for (int m = 0; m < 4; ++m) {
      int row = r0 + g + 16 * m;
      float4 o;
      o.x = fast_exp2(C2F * acc[m][0]);
      o.y = fast_exp2(C2F * acc[m][1]);
      o.z = fast_exp2(C2F * acc[m][2]);
      o.w = fast_exp2(C2F * acc[m][3]);
      *(float4*)&out[((size_t)b * rowsPerB + row) * 64 + 4 * j] = o;
    }
  }
}

// ---------------------------------------------------------------------------
// Fused scores + masked softmax + PV. One block = (batch b, 4 queries).
// wave = query within tile; lane owns k-pair per 128-k tile.
// ---------------------------------------------------------------------------
__global__ __launch_bounds__(256)
void attn_kernel(const float* __restrict__ Eq, const float* __restrict__ EkT,
                 const float* __restrict__ values, const int* __restrict__ vlens,
                 const float* __restrict__ wv, float* __restrict__ out)
{
  const int t    = threadIdx.x;
  const int b    = blockIdx.x & 15;
  const int qt   = blockIdx.x >> 4;   // 0..31
  const int wave = t >> 6;            // query-in-tile
  const int lane = t & 63;

  __shared__ float4 sc4[512 * 4];     // slot (k>>2)*4 + qq
  __shared__ float  pvp[128 * 5];     // pv partial, padded stride 5
  __shared__ float  linvs[4];

  const int vl = vlens[b];

  // load Eq row + wv into registers (statically indexed, fully unrolled)
  float eqv[64], wv2[64];
  float w0 = 0.f;
  {
    const float4* eq4 = (const float4*)(Eq + (size_t)(b * 128 + qt * 4 + wave) * 64);
    const float4* wv4 = (const float4*)wv;
    #pragma unroll
    for (int u = 0; u < 16; ++u) {
      float4 e = eq4[u], v = wv4[u];
      eqv[4*u+0] = e.x; eqv[4*u+1] = e.y; eqv[4*u+2] = e.z; eqv[4*u+3] = e.w;
      wv2[4*u+0] = -2.f * v.x; wv2[4*u+1] = -2.f * v.y;
      wv2[4*u+2] = -2.f * v.z; wv2[4*u+3] = -2.f * v.w;
      w0 += v.x + v.y + v.z + v.w;
    }
  }

  // ---- score phase: tiles of 128 k, lane owns k = kt*128 + 2*lane + {0,1}
  const int ktiles = (vl + 127) >> 7;
  const int kp = 2 * lane;
  for (int kt = 0; kt < ktiles; ++kt) {
    const float* tb = EkT + ((size_t)(b * 16 + kt) * 64) * 128 + kp;
    float s0 = w0, s1 = w0;
    #pragma unroll
    for (int h = 0; h < 64; ++h) {
      float2 ek = *(const float2*)(tb + (size_t)h * 128);
      float r0 = fast_rcp(fmaf(eqv[h], ek.x, 1.0f));
      float r1 = fast_rcp(fmaf(eqv[h], ek.y, 1.0f));
      s0 = fmaf(wv2[h], r0, s0);
      s1 = fmaf(wv2[h], r1, s1);
    }
    int k = kt * 128 + kp;
    if (k     >= vl) s0 = -1e9f;   // unconditional overwrite: poison/NaN safe
    if (k + 1 >= vl) s1 = -1e9f;
    float* scf = (float*)sc4;
    *(float2*)(scf + (((k >> 2) * 4 + wave) * 4 + (k & 3))) = make_float2(s0, s1);
  }

  // ---- softmax (per wave over its own row; no barrier needed before this)
  const int nq4 = (vl + 3) >> 2;
  float mx = -3e38f;
  for (int Q = lane; Q < nq4; Q += 64) {
    float4 f = sc4[Q * 4 + wave];
    mx = fmaxf(mx, fmaxf(fmaxf(f.x, f.y), fmaxf(f.z, f.w)));
  }
  #pragma unroll
  for (int msk = 1; msk < 64; msk <<= 1) mx = fmaxf(mx, __shfl_xor(mx, msk, 64));
  float lsum = 0.f;
  for (int Q = lane; Q < nq4; Q += 64) {
    float4 f = sc4[Q * 4 + wave];
    f.x = fast_exp2((f.x - mx) * L2E);
    f.y = fast_exp2((f.y - mx) * L2E);
    f.z = fast_exp2((f.z - mx) * L2E);
    f.w = fast_exp2((f.w - mx) * L2E);
    sc4[Q * 4 + wave] = f;
    lsum += f.x + f.y + f.z + f.w;
  }
  #pragma unroll
  for (int msk = 1; msk < 64; msk <<= 1) lsum += __shfl_xor(lsum, msk, 64);
  if (lane == 0) linvs[wave] = fast_rcp(lsum);
  __syncthreads();

  // ---- PV: thread = (k-half grp, v); p broadcast from LDS, V coalesced
  const int grp = t >> 7, v = t & 127;
  float acc[4] = {0.f, 0.f, 0.f, 0.f};
  const float* vb = values + (size_t)b * 2048 * 128 + v;
  for (int Q = grp; Q < nq4; Q += 2) {
    float4 p0 = sc4[Q * 4 + 0], p1 = sc4[Q * 4 + 1];
    float4 p2 = sc4[Q * 4 + 2], p3 = sc4[Q * 4 + 3];
    const float* vk = vb + (size_t)(Q * 4) * 128;
    float x;
    x = vk[0];
    acc[0]=fmaf(p0.x,x,acc[0]); acc[1]=fmaf(p1.x,x,acc[1]);
    acc[2]=fmaf(p2.x,x,acc[2]); acc[3]=fmaf(p3.x,x,acc[3]);
    x = vk[128];
    acc[0]=fmaf(p0.y,x,acc[0]); acc[1]=fmaf(p1.y,x,acc[1]);
    acc[2]=fmaf(p2.y,x,acc[2]); acc[3]=fmaf(p3.y,x,acc[3]);
    x = vk[256];
    acc[0]=fmaf(p0.z,x,acc[0]); acc[1]=fmaf(p1.z,x,acc[1]);
    acc[2]=fmaf(p2.z,x,acc[2]); acc[3]=fmaf(p3.z,x,acc[3]);
    x = vk[384];
    acc[0]=fmaf(p0.w,x,acc[0]); acc[1]=fmaf(p1.w,x,acc[1]);
    acc[2]=fmaf(p2.w,x,acc[2]); acc[3]=fmaf(p3.w,x,acc[3]);
  }
  if (grp == 1) {
    #pragma unroll
    for (int qq = 0; qq < 4; ++qq) pvp[v * 5 + qq] = acc[qq];
  }
  __syncthreads();
  if (grp == 0) {
    #pragma unroll
    for (int qq = 0; qq < 4; ++qq) {
      float tot = acc[qq] + pvp[v * 5 + qq];
      out[((size_t)(b * 128) + qt * 4 + qq) * 128 + v] = tot * linvs[qq];
    }
  }
}

// ---------------------------------------------------------------------------
extern "C" void kernel_launch(void* const* d_in, const int* in_sizes, int n_in,
                              void* d_out, int out_size, void* d_ws, size_t ws_size,
                              hipStream_t stream) {
  const float* queries = (const float*)d_in[0];   // [16][128][256]
  const float* keys    = (const float*)d_in[1];   // [16][2048][256]
  const float* values  = (const float*)d_in[2];   // [16][2048][128]
  const int*   vlens   = (const int*)d_in[3];     // [16]
  const float* Wq      = (const float*)d_in[4];   // [256][64]
  const float* Wk      = (const float*)d_in[5];   // [256][64]
  const float* wv      = (const float*)d_in[6];   // [64]
  float* outp = (float*)d_out;

  float* Eq  = (float*)d_ws;                      // 16*128*64 floats
  float* EkT = Eq + 16 * 128 * 64;                // 16*16*64*128 floats

  hipLaunchKernelGGL((proj_kernel<false>), dim3(32),  dim3(256), 0, stream,
                     queries, Wq, Eq, (const int*)nullptr, 128);
  hipLaunchKernelGGL((proj_kernel<true>),  dim3(512), dim3(256), 0, stream,
                     keys, Wk, EkT, vlens, 2048);
  hipLaunchKernelGGL(attn_kernel, dim3(512), dim3(256), 0, stream,
                     Eq, EkT, values, vlens, wv, outp);
}

// Round 2
// 140.257 us; speedup vs baseline: 2.5617x; 2.5617x over previous
//
#include <hip/hip_runtime.h>
#include <stddef.h>

// Additive attention: out = softmax_k(mask(sum_h wv_h * tanh(qW_h + kW_h))) @ V
// tanh(q+k) = 1 - 2/(1 + e^{2q} e^{2k})  -> precompute Eq=e^{2q}, Ek=e^{2k};
// score = W0 + sum_h wv2_h * rcp(1 + Eq_h*Ek_h), wv2 = -2*wv, W0 = sum_h wv_h.
//
// Two-pass: scores -> ws (balanced fine-grained grid), then softmax+PV.
// Falls back to round-1 fused kernel if ws_size < 25.7MB.

__device__ __forceinline__ float fast_rcp(float x)  { return __builtin_amdgcn_rcpf(x); }
__device__ __forceinline__ float fast_exp2(float x) { return __builtin_amdgcn_exp2f(x); }
__device__ __forceinline__ float fast_log2(float x) { return __builtin_amdgcn_logf(x); }

#define C2F 2.88539008177792681f   // 2*log2(e)
#define L2E 1.44269504088896340f   // log2(e)

// ---------------------------------------------------------------------------
// Projection: P = in[rows x 256] @ W[256 x 64], out = exp2(C2F * P)
// TRANSPOSED (keys): out = EkT[((b*16 + (k>>7))*64 + h)*128 + (k&127)]
// else (queries):    out = Eq[(b*rowsPerB + row)*64 + h]
// ---------------------------------------------------------------------------
template<bool TRANSPOSED>
__global__ __launch_bounds__(256)
void proj_kernel(const float* __restrict__ in, const float* __restrict__ W,
                 float* __restrict__ out, const int* __restrict__ vlens,
                 int rowsPerB)
{
  const int t  = threadIdx.x;
  const int b  = blockIdx.x & 15;
  const int rt = blockIdx.x >> 4;
  const int r0 = rt * 64;
  if constexpr (TRANSPOSED) {
    if (r0 >= vlens[b]) return;   // whole block invalid (uniform early exit)
  }

  __shared__ float4 Wlds[256 * 16];   // [d][h-quad]
  __shared__ float  klds[64 * 36];    // [row][d-chunk], padded to 36

  const float4* W4 = (const float4*)W;
  #pragma unroll
  for (int i = 0; i < 16; ++i) Wlds[t + 256 * i] = W4[t + 256 * i];

  const float* inb = in + ((size_t)b * rowsPerB + r0) * 256;
  const int j = t >> 4;
  const int g = t & 15;

  float acc[4][4];
  #pragma unroll
  for (int m = 0; m < 4; ++m)
    acc[m][0] = acc[m][1] = acc[m][2] = acc[m][3] = 0.f;

  for (int dc = 0; dc < 8; ++dc) {
    {
      const int row = t >> 2, cs = (t & 3) * 8;
      const float* s = inb + row * 256 + dc * 32 + cs;
      float4 a0 = *(const float4*)s;
      float4 a1 = *(const float4*)(s + 4);
      float* dst = &klds[row * 36 + cs];
      *(float4*)dst       = a0;
      *(float4*)(dst + 4) = a1;
    }
    __syncthreads();
    #pragma unroll
    for (int d = 0; d < 32; ++d) {
      float4 w4 = Wlds[(dc * 32 + d) * 16 + j];
      #pragma unroll
      for (int m = 0; m < 4; ++m) {
        float kv = klds[(g + 16 * m) * 36 + d];
        acc[m][0] = fmaf(kv, w4.x, acc[m][0]);
        acc[m][1] = fmaf(kv, w4.y, acc[m][1]);
        acc[m][2] = fmaf(kv, w4.z, acc[m][2]);
        acc[m][3] = fmaf(kv, w4.w, acc[m][3]);
      }
    }
    __syncthreads();
  }

  if constexpr (TRANSPOSED) {
    #pragma unroll
    for (int m = 0; m < 4; ++m) {
      int k = r0 + g + 16 * m;
      size_t base = ((size_t)(b * 16 + (k >> 7)) * 64) * 128 + (k & 127);
      #pragma unroll
      for (int i = 0; i < 4; ++i)
        out[base + (size_t)(4 * j + i) * 128] = fast_exp2(C2F * acc[m][i]);
    }
  } else {
    #pragma unroll
    for (int m = 0; m < 4; ++m) {
      int row = r0 + g + 16 * m;
      float4 o;
      o.x = fast_exp2(C2F * acc[m][0]);
      o.y = fast_exp2(C2F * acc[m][1]);
      o.z = fast_exp2(C2F * acc[m][2]);
      o.w = fast_exp2(C2F * acc[m][3]);
      *(float4*)&out[((size_t)b * rowsPerB + row) * 64 + 4 * j] = o;
    }
  }
}

// ---------------------------------------------------------------------------
// Pass 1: scores[b][q][k] for one (b, 128-k tile, 32-q tile).
// Block 256 = 4 waves; wave owns 8 q; lane owns k-pair. Ek+Eq staged in LDS.
// Writes garbage (finite) for k >= vl; pass 2 masks.
// ---------------------------------------------------------------------------
__global__ __launch_bounds__(256)
void scores_kernel(const float* __restrict__ Eq, const float* __restrict__ EkT,
                   const int* __restrict__ vlens, const float* __restrict__ wv,
                   float* __restrict__ scores)
{
  const int blk = blockIdx.x;          // b*64 + kt*4 + qq
  const int b   = blk >> 6;
  const int kt  = (blk >> 2) & 15;
  const int qq  = blk & 3;
  const int vl  = vlens[b];
  if (kt * 128 >= vl) return;

  __shared__ float ek_lds[64 * 128];   // [h][k]  32KB (contiguous from EkT)
  __shared__ float eq_lds[32 * 64];    // [q][h]   8KB
  __shared__ float wv2_lds[64];

  const int t = threadIdx.x;

  // w0 = sum_h wv[h] (global reads, broadcast/cached)
  float w0 = 0.f;
  {
    const float4* wv4 = (const float4*)wv;
    #pragma unroll
    for (int u = 0; u < 16; ++u) {
      float4 v = wv4[u];
      w0 += v.x + v.y + v.z + v.w;
    }
  }

  {
    const float4* src = (const float4*)(EkT + ((size_t)(b * 16 + kt) * 64) * 128);
    float4* dst = (float4*)ek_lds;
    #pragma unroll
    for (int i = 0; i < 8; ++i) dst[t + 256 * i] = src[t + 256 * i];
    const float4* qsrc = (const float4*)(Eq + (size_t)(b * 128 + qq * 32) * 64);
    float4* qdst = (float4*)eq_lds;
    qdst[t] = qsrc[t];
    qdst[t + 256] = qsrc[t + 256];
    if (t < 64) wv2_lds[t] = -2.0f * wv[t];
  }
  __syncthreads();

  const int q0l = (t >> 6) * 8;        // wave's local q base
  const int kp  = (t & 63) * 2;        // lane's k pair

  float s[8][2];
  #pragma unroll
  for (int q = 0; q < 8; ++q) { s[q][0] = w0; s[q][1] = w0; }

  #pragma unroll 2
  for (int h = 0; h < 64; ++h) {
    float2 ek = *(const float2*)&ek_lds[h * 128 + kp];
    float wvh = wv2_lds[h];
    #pragma unroll
    for (int q = 0; q < 8; ++q) {
      float eq = eq_lds[(q0l + q) * 64 + h];
      s[q][0] = fmaf(wvh, fast_rcp(fmaf(eq, ek.x, 1.0f)), s[q][0]);
      s[q][1] = fmaf(wvh, fast_rcp(fmaf(eq, ek.y, 1.0f)), s[q][1]);
    }
  }

  const int qg0 = qq * 32 + q0l;
  #pragma unroll
  for (int q = 0; q < 8; ++q) {
    *(float2*)&scores[((size_t)(b * 128 + qg0 + q)) * 2048 + kt * 128 + kp] =
        make_float2(s[q][0], s[q][1]);
  }
}

// ---------------------------------------------------------------------------
// Pass 2: masked softmax + PV for one (b, 8-q tile). Block 512 = 8 waves.
// Phase A: wave w -> softmax stats of q=qt*8+w. Phase B: thread (kg, v),
// p broadcast from LDS, V coalesced, 4-way k-split reduced via LDS.
// ---------------------------------------------------------------------------
__global__ __launch_bounds__(512)
void softpv_kernel(const float* __restrict__ scores, const float* __restrict__ values,
                   const int* __restrict__ vlens, float* __restrict__ out)
{
  const int b  = blockIdx.x >> 4;
  const int qt = blockIdx.x & 15;
  const int vl = vlens[b];
  const int t = threadIdx.x;
  const int wave = t >> 6, lane = t & 63;

  __shared__ float offs[8];
  __shared__ float p_lds[64 * 8];        // [k][q]
  __shared__ float part[8 * 4 * 128];    // [q][kg][v]

  // ---- phase A: softmax stats, wave -> its own q row
  const float* srow = scores + ((size_t)(b * 128 + qt * 8 + wave)) * 2048;
  float mx = -3e38f;
  for (int k = lane; k < vl; k += 64) mx = fmaxf(mx, srow[k]);
  #pragma unroll
  for (int m = 1; m < 64; m <<= 1) mx = fmaxf(mx, __shfl_xor(mx, m, 64));
  float sum = 0.f;
  for (int k = lane; k < vl; k += 64) sum += fast_exp2((srow[k] - mx) * L2E);
  #pragma unroll
  for (int m = 1; m < 64; m <<= 1) sum += __shfl_xor(sum, m, 64);
  if (lane == 0) offs[wave] = mx * L2E + fast_log2(sum);
  __syncthreads();

  // ---- phase B: PV
  const int kg = t >> 7, v = t & 127;
  const int pq = t >> 6, pk = t & 63;    // for p computation
  const float* prow = scores + ((size_t)(b * 128 + qt * 8 + pq)) * 2048;
  float acc[8] = {0.f, 0.f, 0.f, 0.f, 0.f, 0.f, 0.f, 0.f};
  const float* vb = values + (size_t)b * 2048 * 128 + v;

  for (int kt0 = 0; kt0 < vl; kt0 += 64) {
    {
      int k = kt0 + pk;
      float sv = prow[k];                                 // k < 2048 always
      float p = (k < vl) ? fast_exp2(fmaf(sv, L2E, -offs[pq])) : 0.f;
      p_lds[pk * 8 + pq] = p;
    }
    __syncthreads();
    #pragma unroll 4
    for (int i = 0; i < 16; ++i) {
      int kl = kg * 16 + i;
      float vx = vb[(size_t)(kt0 + kl) * 128];
      float4 pa = *(const float4*)&p_lds[kl * 8 + 0];
      float4 pb = *(const float4*)&p_lds[kl * 8 + 4];
      acc[0] = fmaf(pa.x, vx, acc[0]); acc[1] = fmaf(pa.y, vx, acc[1]);
      acc[2] = fmaf(pa.z, vx, acc[2]); acc[3] = fmaf(pa.w, vx, acc[3]);
      acc[4] = fmaf(pb.x, vx, acc[4]); acc[5] = fmaf(pb.y, vx, acc[5]);
      acc[6] = fmaf(pb.z, vx, acc[6]); acc[7] = fmaf(pb.w, vx, acc[7]);
    }
    __syncthreads();
  }

  #pragma unroll
  for (int q = 0; q < 8; ++q) part[(q * 4 + kg) * 128 + v] = acc[q];
  __syncthreads();
  #pragma unroll
  for (int j0 = 0; j0 < 2; ++j0) {
    int j = t + j0 * 512;
    int q = j >> 7, vv = j & 127;
    float tot = part[(q * 4 + 0) * 128 + vv] + part[(q * 4 + 1) * 128 + vv]
              + part[(q * 4 + 2) * 128 + vv] + part[(q * 4 + 3) * 128 + vv];
    out[((size_t)(b * 128 + qt * 8 + q)) * 128 + vv] = tot;
  }
}

// ---------------------------------------------------------------------------
// Fallback fused kernel (round-1, known-correct) for small ws_size.
// ---------------------------------------------------------------------------
__global__ __launch_bounds__(256)
void attn_kernel(const float* __restrict__ Eq, const float* __restrict__ EkT,
                 const float* __restrict__ values, const int* __restrict__ vlens,
                 const float* __restrict__ wv, float* __restrict__ out)
{
  const int t    = threadIdx.x;
  const int b    = blockIdx.x & 15;
  const int qt   = blockIdx.x >> 4;
  const int wave = t >> 6;
  const int lane = t & 63;

  __shared__ float4 sc4[512 * 4];
  __shared__ float  pvp[128 * 5];
  __shared__ float  linvs[4];

  const int vl = vlens[b];

  float eqv[64], wv2[64];
  float w0 = 0.f;
  {
    const float4* eq4 = (const float4*)(Eq + (size_t)(b * 128 + qt * 4 + wave) * 64);
    const float4* wv4 = (const float4*)wv;
    #pragma unroll
    for (int u = 0; u < 16; ++u) {
      float4 e = eq4[u], v = wv4[u];
      eqv[4*u+0] = e.x; eqv[4*u+1] = e.y; eqv[4*u+2] = e.z; eqv[4*u+3] = e.w;
      wv2[4*u+0] = -2.f * v.x; wv2[4*u+1] = -2.f * v.y;
      wv2[4*u+2] = -2.f * v.z; wv2[4*u+3] = -2.f * v.w;
      w0 += v.x + v.y + v.z + v.w;
    }
  }

  const int ktiles = (vl + 127) >> 7;
  const int kp = 2 * lane;
  for (int kt = 0; kt < ktiles; ++kt) {
    const float* tb = EkT + ((size_t)(b * 16 + kt) * 64) * 128 + kp;
    float s0 = w0, s1 = w0;
    #pragma unroll
    for (int h = 0; h < 64; ++h) {
      float2 ek = *(const float2*)(tb + (size_t)h * 128);
      float r0 = fast_rcp(fmaf(eqv[h], ek.x, 1.0f));
      float r1 = fast_rcp(fmaf(eqv[h], ek.y, 1.0f));
      s0 = fmaf(wv2[h], r0, s0);
      s1 = fmaf(wv2[h], r1, s1);
    }
    int k = kt * 128 + kp;
    if (k     >= vl) s0 = -1e9f;
    if (k + 1 >= vl) s1 = -1e9f;
    float* scf = (float*)sc4;
    *(float2*)(scf + (((k >> 2) * 4 + wave) * 4 + (k & 3))) = make_float2(s0, s1);
  }

  const int nq4 = (vl + 3) >> 2;
  float mx = -3e38f;
  for (int Q = lane; Q < nq4; Q += 64) {
    float4 f = sc4[Q * 4 + wave];
    mx = fmaxf(mx, fmaxf(fmaxf(f.x, f.y), fmaxf(f.z, f.w)));
  }
  #pragma unroll
  for (int msk = 1; msk < 64; msk <<= 1) mx = fmaxf(mx, __shfl_xor(mx, msk, 64));
  float lsum = 0.f;
  for (int Q = lane; Q < nq4; Q += 64) {
    float4 f = sc4[Q * 4 + wave];
    f.x = fast_exp2((f.x - mx) * L2E);
    f.y = fast_exp2((f.y - mx) * L2E);
    f.z = fast_exp2((f.z - mx) * L2E);
    f.w = fast_exp2((f.w - mx) * L2E);
    sc4[Q * 4 + wave] = f;
    lsum += f.x + f.y + f.z + f.w;
  }
  #pragma unroll
  for (int msk = 1; msk < 64; msk <<= 1) lsum += __shfl_xor(lsum, msk, 64);
  if (lane == 0) linvs[wave] = fast_rcp(lsum);
  __syncthreads();

  const int grp = t >> 7, v = t & 127;
  float acc[4] = {0.f, 0.f, 0.f, 0.f};
  const float* vb = values + (size_t)b * 2048 * 128 + v;
  for (int Q = grp; Q < nq4; Q += 2) {
    float4 p0 = sc4[Q * 4 + 0], p1 = sc4[Q * 4 + 1];
    float4 p2 = sc4[Q * 4 + 2], p3 = sc4[Q * 4 + 3];
    const float* vk = vb + (size_t)(Q * 4) * 128;
    float x;
    x = vk[0];
    acc[0]=fmaf(p0.x,x,acc[0]); acc[1]=fmaf(p1.x,x,acc[1]);
    acc[2]=fmaf(p2.x,x,acc[2]); acc[3]=fmaf(p3.x,x,acc[3]);
    x = vk[128];
    acc[0]=fmaf(p0.y,x,acc[0]); acc[1]=fmaf(p1.y,x,acc[1]);
    acc[2]=fmaf(p2.y,x,acc[2]); acc[3]=fmaf(p3.y,x,acc[3]);
    x = vk[256];
    acc[0]=fmaf(p0.z,x,acc[0]); acc[1]=fmaf(p1.z,x,acc[1]);
    acc[2]=fmaf(p2.z,x,acc[2]); acc[3]=fmaf(p3.z,x,acc[3]);
    x = vk[384];
    acc[0]=fmaf(p0.w,x,acc[0]); acc[1]=fmaf(p1.w,x,acc[1]);
    acc[2]=fmaf(p2.w,x,acc[2]); acc[3]=fmaf(p3.w,x,acc[3]);
  }
  if (grp == 1) {
    #pragma unroll
    for (int qq = 0; qq < 4; ++qq) pvp[v * 5 + qq] = acc[qq];
  }
  __syncthreads();
  if (grp == 0) {
    #pragma unroll
    for (int qq = 0; qq < 4; ++qq) {
      float tot = acc[qq] + pvp[v * 5 + qq];
      out[((size_t)(b * 128) + qt * 4 + qq) * 128 + v] = tot * linvs[qq];
    }
  }
}

// ---------------------------------------------------------------------------
extern "C" void kernel_launch(void* const* d_in, const int* in_sizes, int n_in,
                              void* d_out, int out_size, void* d_ws, size_t ws_size,
                              hipStream_t stream) {
  const float* queries = (const float*)d_in[0];   // [16][128][256]
  const float* keys    = (const float*)d_in[1];   // [16][2048][256]
  const float* values  = (const float*)d_in[2];   // [16][2048][128]
  const int*   vlens   = (const int*)d_in[3];     // [16]
  const float* Wq      = (const float*)d_in[4];   // [256][64]
  const float* Wk      = (const float*)d_in[5];   // [256][64]
  const float* wv      = (const float*)d_in[6];   // [64]
  float* outp = (float*)d_out;

  float* Eq     = (float*)d_ws;                   // 16*128*64       = 131072 f
  float* EkT    = Eq + 16 * 128 * 64;             // 16*16*64*128    = 2097152 f
  float* scores = EkT + 16 * 16 * 64 * 128;       // 16*128*2048     = 4194304 f
  const size_t need = (size_t)(131072 + 2097152 + 4194304) * 4;

  hipLaunchKernelGGL((proj_kernel<false>), dim3(32),  dim3(256), 0, stream,
                     queries, Wq, Eq, (const int*)nullptr, 128);
  hipLaunchKernelGGL((proj_kernel<true>),  dim3(512), dim3(256), 0, stream,
                     keys, Wk, EkT, vlens, 2048);

  if (ws_size >= need) {
    hipLaunchKernelGGL(scores_kernel, dim3(1024), dim3(256), 0, stream,
                       Eq, EkT, vlens, wv, scores);
    hipLaunchKernelGGL(softpv_kernel, dim3(256), dim3(512), 0, stream,
                       scores, values, vlens, outp);
  } else {
    hipLaunchKernelGGL(attn_kernel, dim3(512), dim3(256), 0, stream,
                       Eq, EkT, values, vlens, wv, outp);
  }
}

// Round 3
// 115.211 us; speedup vs baseline: 3.1186x; 1.2174x over previous
//
#include <hip/hip_runtime.h>
#include <stddef.h>

// Additive attention: out = softmax_k(mask(sum_h wv_h * tanh(qW_h + kW_h))) @ V
// tanh(q+k) = 1 - 2/(1 + e^{2q} e^{2k})  -> precompute Eq=e^{2q}, Ek=e^{2k};
// score = W0 + sum_h wv2_h * rcp(1 + Eq_h*Ek_h), wv2 = -2*wv, W0 = sum_h wv_h.
//
// Pipeline: projq, projk -> scores(+tile softmax stats) -> combine(offs)
//           -> pv_partial (k-split) -> pv_reduce.

__device__ __forceinline__ float fast_rcp(float x)  { return __builtin_amdgcn_rcpf(x); }
__device__ __forceinline__ float fast_exp2(float x) { return __builtin_amdgcn_exp2f(x); }
__device__ __forceinline__ float fast_log2(float x) { return __builtin_amdgcn_logf(x); }

#define C2F 2.88539008177792681f   // 2*log2(e)
#define L2E 1.44269504088896340f   // log2(e)

// ---------------------------------------------------------------------------
// Projection: P = in[rows x 256] @ W[256 x 64], out = exp2(C2F * P)
// ---------------------------------------------------------------------------
template<bool TRANSPOSED>
__global__ __launch_bounds__(256)
void proj_kernel(const float* __restrict__ in, const float* __restrict__ W,
                 float* __restrict__ out, const int* __restrict__ vlens,
                 int rowsPerB)
{
  const int t  = threadIdx.x;
  const int b  = blockIdx.x & 15;
  const int rt = blockIdx.x >> 4;
  const int r0 = rt * 64;
  if constexpr (TRANSPOSED) {
    if (r0 >= vlens[b]) return;
  }

  __shared__ float4 Wlds[256 * 16];   // [d][h-quad]
  __shared__ float  klds[64 * 36];

  const float4* W4 = (const float4*)W;
  #pragma unroll
  for (int i = 0; i < 16; ++i) Wlds[t + 256 * i] = W4[t + 256 * i];

  const float* inb = in + ((size_t)b * rowsPerB + r0) * 256;
  const int j = t >> 4;
  const int g = t & 15;

  float acc[4][4];
  #pragma unroll
  for (int m = 0; m < 4; ++m)
    acc[m][0] = acc[m][1] = acc[m][2] = acc[m][3] = 0.f;

  for (int dc = 0; dc < 8; ++dc) {
    {
      const int row = t >> 2, cs = (t & 3) * 8;
      const float* s = inb + row * 256 + dc * 32 + cs;
      float4 a0 = *(const float4*)s;
      float4 a1 = *(const float4*)(s + 4);
      float* dst = &klds[row * 36 + cs];
      *(float4*)dst       = a0;
      *(float4*)(dst + 4) = a1;
    }
    __syncthreads();
    #pragma unroll
    for (int d = 0; d < 32; ++d) {
      float4 w4 = Wlds[(dc * 32 + d) * 16 + j];
      #pragma unroll
      for (int m = 0; m < 4; ++m) {
        float kv = klds[(g + 16 * m) * 36 + d];
        acc[m][0] = fmaf(kv, w4.x, acc[m][0]);
        acc[m][1] = fmaf(kv, w4.y, acc[m][1]);
        acc[m][2] = fmaf(kv, w4.z, acc[m][2]);
        acc[m][3] = fmaf(kv, w4.w, acc[m][3]);
      }
    }
    __syncthreads();
  }

  if constexpr (TRANSPOSED) {
    #pragma unroll
    for (int m = 0; m < 4; ++m) {
      int k = r0 + g + 16 * m;
      size_t base = ((size_t)(b * 16 + (k >> 7)) * 64) * 128 + (k & 127);
      #pragma unroll
      for (int i = 0; i < 4; ++i)
        out[base + (size_t)(4 * j + i) * 128] = fast_exp2(C2F * acc[m][i]);
    }
  } else {
    #pragma unroll
    for (int m = 0; m < 4; ++m) {
      int row = r0 + g + 16 * m;
      float4 o;
      o.x = fast_exp2(C2F * acc[m][0]);
      o.y = fast_exp2(C2F * acc[m][1]);
      o.z = fast_exp2(C2F * acc[m][2]);
      o.w = fast_exp2(C2F * acc[m][3]);
      *(float4*)&out[((size_t)b * rowsPerB + row) * 64 + 4 * j] = o;
    }
  }
}

// ---------------------------------------------------------------------------
// Scores + per-tile softmax stats. Block = (b, 128-k tile, 16-q tile), 256 thr.
// Wave owns 4 q, lane owns k-pair. Stats: tmax/tsum[b][kt][q].
// ---------------------------------------------------------------------------
__global__ __launch_bounds__(256)
void scores_kernel(const float* __restrict__ Eq, const float* __restrict__ EkT,
                   const int* __restrict__ vlens, const float* __restrict__ wv,
                   float* __restrict__ scores, float* __restrict__ tmax,
                   float* __restrict__ tsum)
{
  const int blk = blockIdx.x;          // b*128 + kt*8 + qq
  const int b   = blk >> 7;
  const int kt  = (blk >> 3) & 15;
  const int qq  = blk & 7;
  const int vl  = vlens[b];
  if (kt * 128 >= vl) return;

  __shared__ float ek_lds[64 * 128];   // [h][k]  32KB
  __shared__ float eq_lds[16 * 64];    // [q][h]   4KB
  __shared__ float wv2_lds[64];

  const int t = threadIdx.x;

  float w0 = 0.f;
  {
    const float4* wv4 = (const float4*)wv;
    #pragma unroll
    for (int u = 0; u < 16; ++u) {
      float4 v = wv4[u];
      w0 += v.x + v.y + v.z + v.w;
    }
  }

  {
    const float4* src = (const float4*)(EkT + ((size_t)(b * 16 + kt) * 64) * 128);
    float4* dst = (float4*)ek_lds;
    #pragma unroll
    for (int i = 0; i < 8; ++i) dst[t + 256 * i] = src[t + 256 * i];
    const float4* qsrc = (const float4*)(Eq + (size_t)(b * 128 + qq * 16) * 64);
    ((float4*)eq_lds)[t] = qsrc[t];
    if (t < 64) wv2_lds[t] = -2.0f * wv[t];
  }
  __syncthreads();

  const int wave = t >> 6, lane = t & 63;
  const int q0l = wave * 4;
  const int kp  = lane * 2;

  float s[4][2];
  #pragma unroll
  for (int q = 0; q < 4; ++q) { s[q][0] = w0; s[q][1] = w0; }

  #pragma unroll 4
  for (int h = 0; h < 64; ++h) {
    float2 ek = *(const float2*)&ek_lds[h * 128 + kp];
    float wvh = wv2_lds[h];
    #pragma unroll
    for (int q = 0; q < 4; ++q) {
      float eq = eq_lds[(q0l + q) * 64 + h];
      s[q][0] = fmaf(wvh, fast_rcp(fmaf(eq, ek.x, 1.0f)), s[q][0]);
      s[q][1] = fmaf(wvh, fast_rcp(fmaf(eq, ek.y, 1.0f)), s[q][1]);
    }
  }

  // mask beyond vl (unconditional overwrite: poison-safe)
  const int kbase = kt * 128 + kp;
  #pragma unroll
  for (int q = 0; q < 4; ++q) {
    if (kbase     >= vl) s[q][0] = -1e9f;
    if (kbase + 1 >= vl) s[q][1] = -1e9f;
  }

  const int qg0 = qq * 16 + q0l;
  #pragma unroll
  for (int q = 0; q < 4; ++q) {
    *(float2*)&scores[((size_t)(b * 128 + qg0 + q)) * 2048 + kbase] =
        make_float2(s[q][0], s[q][1]);
  }

  // per-tile stats (wave owns its q rows exclusively)
  #pragma unroll
  for (int q = 0; q < 4; ++q) {
    float m = fmaxf(s[q][0], s[q][1]);
    #pragma unroll
    for (int msk = 1; msk < 64; msk <<= 1) m = fmaxf(m, __shfl_xor(m, msk, 64));
    float e = fast_exp2((s[q][0] - m) * L2E) + fast_exp2((s[q][1] - m) * L2E);
    #pragma unroll
    for (int msk = 1; msk < 64; msk <<= 1) e += __shfl_xor(e, msk, 64);
    if (lane == 0) {
      tmax[(size_t)(b * 16 + kt) * 128 + qg0 + q] = m;
      tsum[(size_t)(b * 16 + kt) * 128 + qg0 + q] = e;
    }
  }
}

// ---------------------------------------------------------------------------
// Combine per-tile stats -> offs[b][q] = M*L2E + log2(sum)  (p = exp2(s*L2E-offs))
// ---------------------------------------------------------------------------
__global__ __launch_bounds__(128)
void combine_kernel(const float* __restrict__ tmax, const float* __restrict__ tsum,
                    const int* __restrict__ vlens, float* __restrict__ offs)
{
  const int b = blockIdx.x;
  const int q = threadIdx.x;
  const int ntk = (vlens[b] + 127) >> 7;
  float M = -3e38f;
  for (int i = 0; i < ntk; ++i)
    M = fmaxf(M, tmax[(size_t)(b * 16 + i) * 128 + q]);
  float tot = 0.f;
  for (int i = 0; i < ntk; ++i)
    tot += tsum[(size_t)(b * 16 + i) * 128 + q] *
           fast_exp2((tmax[(size_t)(b * 16 + i) * 128 + q] - M) * L2E);
  offs[b * 128 + q] = M * L2E + fast_log2(tot);
}

// ---------------------------------------------------------------------------
// PV partial: block = (b, 8-q tile, 512-k chunk), 512 thr.
// Thread (kg,v); p broadcast via LDS; partial[b][qt][kc][q][v] -> ws.
// ---------------------------------------------------------------------------
__global__ __launch_bounds__(512)
void pv_partial(const float* __restrict__ scores, const float* __restrict__ offs,
                const float* __restrict__ values, const int* __restrict__ vlens,
                float* __restrict__ partial)
{
  const int blk = blockIdx.x;          // b*64 + qt*4 + kc
  const int b  = blk >> 6;
  const int qt = (blk >> 2) & 15;
  const int kc = blk & 3;
  const int vl = vlens[b];
  if (kc * 512 >= vl) return;

  __shared__ float offs_l[8];
  __shared__ float p_lds[64 * 8];      // [k][q]
  __shared__ float part_l[8 * 4 * 128];

  const int t = threadIdx.x;
  if (t < 8) offs_l[t] = offs[b * 128 + qt * 8 + t];
  __syncthreads();

  const int kg = t >> 7, v = t & 127;
  const int pq = t >> 6, pk = t & 63;
  const float* prow = scores + ((size_t)(b * 128 + qt * 8 + pq)) * 2048;
  const float* vb = values + (size_t)b * 2048 * 128 + v;
  float acc[8] = {0.f, 0.f, 0.f, 0.f, 0.f, 0.f, 0.f, 0.f};

  const int kend = min(kc * 512 + 512, vl);
  for (int kt0 = kc * 512; kt0 < kend; kt0 += 64) {
    {
      int k = kt0 + pk;
      float sv = prow[k];                       // k < 2048 always valid memory
      float p = (k < vl) ? fast_exp2(fmaf(sv, L2E, -offs_l[pq])) : 0.f;
      p_lds[pk * 8 + pq] = p;
    }
    __syncthreads();
    #pragma unroll
    for (int i = 0; i < 16; ++i) {
      int kl = kg * 16 + i;
      float vx = vb[(size_t)(kt0 + kl) * 128];
      float4 pa = *(const float4*)&p_lds[kl * 8 + 0];
      float4 pb = *(const float4*)&p_lds[kl * 8 + 4];
      acc[0] = fmaf(pa.x, vx, acc[0]); acc[1] = fmaf(pa.y, vx, acc[1]);
      acc[2] = fmaf(pa.z, vx, acc[2]); acc[3] = fmaf(pa.w, vx, acc[3]);
      acc[4] = fmaf(pb.x, vx, acc[4]); acc[5] = fmaf(pb.y, vx, acc[5]);
      acc[6] = fmaf(pb.z, vx, acc[6]); acc[7] = fmaf(pb.w, vx, acc[7]);
    }
    __syncthreads();
  }

  #pragma unroll
  for (int q = 0; q < 8; ++q) part_l[(q * 4 + kg) * 128 + v] = acc[q];
  __syncthreads();
  #pragma unroll
  for (int j0 = 0; j0 < 2; ++j0) {
    int j = t + j0 * 512;
    int q = j >> 7, vv = j & 127;
    float tot = part_l[(q * 4 + 0) * 128 + vv] + part_l[(q * 4 + 1) * 128 + vv]
              + part_l[(q * 4 + 2) * 128 + vv] + part_l[(q * 4 + 3) * 128 + vv];
    partial[(size_t)blk * 1024 + q * 128 + vv] = tot;
  }
}

// ---------------------------------------------------------------------------
// Reduce k-chunk partials -> out
// ---------------------------------------------------------------------------
__global__ __launch_bounds__(512)
void pv_reduce(const float* __restrict__ partial, const int* __restrict__ vlens,
               float* __restrict__ out)
{
  const int blk = blockIdx.x;          // b*16 + qt
  const int b  = blk >> 4;
  const int qt = blk & 15;
  const int nc = min(4, (vlens[b] + 511) >> 9);
  const int t = threadIdx.x;
  #pragma unroll
  for (int j0 = 0; j0 < 2; ++j0) {
    int j = t + j0 * 512;
    int q = j >> 7, v = j & 127;
    const float* pp = partial + (size_t)(blk * 4) * 1024 + q * 128 + v;
    float s = 0.f;
    for (int c = 0; c < nc; ++c) s += pp[(size_t)c * 1024];
    out[((size_t)(b * 128 + qt * 8 + q)) * 128 + v] = s;
  }
}

// ---------------------------------------------------------------------------
// Fallback fused kernel (round-1, known-correct) for small ws_size.
// ---------------------------------------------------------------------------
__global__ __launch_bounds__(256)
void attn_kernel(const float* __restrict__ Eq, const float* __restrict__ EkT,
                 const float* __restrict__ values, const int* __restrict__ vlens,
                 const float* __restrict__ wv, float* __restrict__ out)
{
  const int t    = threadIdx.x;
  const int b    = blockIdx.x & 15;
  const int qt   = blockIdx.x >> 4;
  const int wave = t >> 6;
  const int lane = t & 63;

  __shared__ float4 sc4[512 * 4];
  __shared__ float  pvp[128 * 5];
  __shared__ float  linvs[4];

  const int vl = vlens[b];

  float eqv[64], wv2[64];
  float w0 = 0.f;
  {
    const float4* eq4 = (const float4*)(Eq + (size_t)(b * 128 + qt * 4 + wave) * 64);
    const float4* wv4 = (const float4*)wv;
    #pragma unroll
    for (int u = 0; u < 16; ++u) {
      float4 e = eq4[u], v = wv4[u];
      eqv[4*u+0] = e.x; eqv[4*u+1] = e.y; eqv[4*u+2] = e.z; eqv[4*u+3] = e.w;
      wv2[4*u+0] = -2.f * v.x; wv2[4*u+1] = -2.f * v.y;
      wv2[4*u+2] = -2.f * v.z; wv2[4*u+3] = -2.f * v.w;
      w0 += v.x + v.y + v.z + v.w;
    }
  }

  const int ktiles = (vl + 127) >> 7;
  const int kp = 2 * lane;
  for (int kt = 0; kt < ktiles; ++kt) {
    const float* tb = EkT + ((size_t)(b * 16 + kt) * 64) * 128 + kp;
    float s0 = w0, s1 = w0;
    #pragma unroll
    for (int h = 0; h < 64; ++h) {
      float2 ek = *(const float2*)(tb + (size_t)h * 128);
      float r0 = fast_rcp(fmaf(eqv[h], ek.x, 1.0f));
      float r1 = fast_rcp(fmaf(eqv[h], ek.y, 1.0f));
      s0 = fmaf(wv2[h], r0, s0);
      s1 = fmaf(wv2[h], r1, s1);
    }
    int k = kt * 128 + kp;
    if (k     >= vl) s0 = -1e9f;
    if (k + 1 >= vl) s1 = -1e9f;
    float* scf = (float*)sc4;
    *(float2*)(scf + (((k >> 2) * 4 + wave) * 4 + (k & 3))) = make_float2(s0, s1);
  }

  const int nq4 = (vl + 3) >> 2;
  float mx = -3e38f;
  for (int Q = lane; Q < nq4; Q += 64) {
    float4 f = sc4[Q * 4 + wave];
    mx = fmaxf(mx, fmaxf(fmaxf(f.x, f.y), fmaxf(f.z, f.w)));
  }
  #pragma unroll
  for (int msk = 1; msk < 64; msk <<= 1) mx = fmaxf(mx, __shfl_xor(mx, msk, 64));
  float lsum = 0.f;
  for (int Q = lane; Q < nq4; Q += 64) {
    float4 f = sc4[Q * 4 + wave];
    f.x = fast_exp2((f.x - mx) * L2E);
    f.y = fast_exp2((f.y - mx) * L2E);
    f.z = fast_exp2((f.z - mx) * L2E);
    f.w = fast_exp2((f.w - mx) * L2E);
    sc4[Q * 4 + wave] = f;
    lsum += f.x + f.y + f.z + f.w;
  }
  #pragma unroll
  for (int msk = 1; msk < 64; msk <<= 1) lsum += __shfl_xor(lsum, msk, 64);
  if (lane == 0) linvs[wave] = fast_rcp(lsum);
  __syncthreads();

  const int grp = t >> 7, v = t & 127;
  float acc[4] = {0.f, 0.f, 0.f, 0.f};
  const float* vb = values + (size_t)b * 2048 * 128 + v;
  for (int Q = grp; Q < nq4; Q += 2) {
    float4 p0 = sc4[Q * 4 + 0], p1 = sc4[Q * 4 + 1];
    float4 p2 = sc4[Q * 4 + 2], p3 = sc4[Q * 4 + 3];
    const float* vk = vb + (size_t)(Q * 4) * 128;
    float x;
    x = vk[0];
    acc[0]=fmaf(p0.x,x,acc[0]); acc[1]=fmaf(p1.x,x,acc[1]);
    acc[2]=fmaf(p2.x,x,acc[2]); acc[3]=fmaf(p3.x,x,acc[3]);
    x = vk[128];
    acc[0]=fmaf(p0.y,x,acc[0]); acc[1]=fmaf(p1.y,x,acc[1]);
    acc[2]=fmaf(p2.y,x,acc[2]); acc[3]=fmaf(p3.y,x,acc[3]);
    x = vk[256];
    acc[0]=fmaf(p0.z,x,acc[0]); acc[1]=fmaf(p1.z,x,acc[1]);
    acc[2]=fmaf(p2.z,x,acc[2]); acc[3]=fmaf(p3.z,x,acc[3]);
    x = vk[384];
    acc[0]=fmaf(p0.w,x,acc[0]); acc[1]=fmaf(p1.w,x,acc[1]);
    acc[2]=fmaf(p2.w,x,acc[2]); acc[3]=fmaf(p3.w,x,acc[3]);
  }
  if (grp == 1) {
    #pragma unroll
    for (int qq = 0; qq < 4; ++qq) pvp[v * 5 + qq] = acc[qq];
  }
  __syncthreads();
  if (grp == 0) {
    #pragma unroll
    for (int qq = 0; qq < 4; ++qq) {
      float tot = acc[qq] + pvp[v * 5 + qq];
      out[((size_t)(b * 128) + qt * 4 + qq) * 128 + v] = tot * linvs[qq];
    }
  }
}

// ---------------------------------------------------------------------------
extern "C" void kernel_launch(void* const* d_in, const int* in_sizes, int n_in,
                              void* d_out, int out_size, void* d_ws, size_t ws_size,
                              hipStream_t stream) {
  const float* queries = (const float*)d_in[0];   // [16][128][256]
  const float* keys    = (const float*)d_in[1];   // [16][2048][256]
  const float* values  = (const float*)d_in[2];   // [16][2048][128]
  const int*   vlens   = (const int*)d_in[3];     // [16]
  const float* Wq      = (const float*)d_in[4];   // [256][64]
  const float* Wk      = (const float*)d_in[5];   // [256][64]
  const float* wv      = (const float*)d_in[6];   // [64]
  float* outp = (float*)d_out;

  float* base    = (float*)d_ws;
  float* Eq      = base;                           // 131072 f
  float* EkT     = base + 131072;                  // 2097152 f
  float* scores  = base + 2228224;                 // 4194304 f
  float* tmaxb   = base + 6422528;                 // 32768 f  [b][kt][q]
  float* tsumb   = base + 6455296;                 // 32768 f
  float* offs    = base + 6488064;                 // 2048 f
  float* partial = base;                           // 1048576 f (aliases Eq/EkT,
                                                   //  dead after scores_kernel)
  const size_t need = (size_t)(6488064 + 2048) * 4;

  hipLaunchKernelGGL((proj_kernel<false>), dim3(32),  dim3(256), 0, stream,
                     queries, Wq, Eq, (const int*)nullptr, 128);
  hipLaunchKernelGGL((proj_kernel<true>),  dim3(512), dim3(256), 0, stream,
                     keys, Wk, EkT, vlens, 2048);

  if (ws_size >= need) {
    hipLaunchKernelGGL(scores_kernel, dim3(2048), dim3(256), 0, stream,
                       Eq, EkT, vlens, wv, scores, tmaxb, tsumb);
    hipLaunchKernelGGL(combine_kernel, dim3(16), dim3(128), 0, stream,
                       tmaxb, tsumb, vlens, offs);
    hipLaunchKernelGGL(pv_partial, dim3(1024), dim3(512), 0, stream,
                       scores, offs, values, vlens, partial);
    hipLaunchKernelGGL(pv_reduce, dim3(256), dim3(512), 0, stream,
                       partial, vlens, outp);
  } else {
    hipLaunchKernelGGL(attn_kernel, dim3(512), dim3(256), 0, stream,
                       Eq, EkT, values, vlens, wv, outp);
  }
}

// Round 4
// 100.443 us; speedup vs baseline: 3.5771x; 1.1470x over previous
//
#include <hip/hip_runtime.h>
#include <stddef.h>

// Additive attention: out = softmax_k(mask(sum_h wv_h * tanh(qW_h + kW_h))) @ V
// tanh(q+k) = 1 - 2/(1 + e^{2q} e^{2k})  -> precompute Eq=e^{2q}, Ek=e^{2k};
// score = W0 + sum_h wv2_h * rcp(1 + Eq_h*Ek_h), wv2 = -2*wv, W0 = sum_h wv_h.
// |score| <= W1 = sum_h |wv_h|  ->  softmax without a global max pass:
//   p = exp2((s - W1)*L2E) in [e^{-2W1}, 1]; normalize by the total sum at the end.
//
// Pipeline: projq, projk -> fused scores+exp+PV partials (k-tile) -> reduce.

__device__ __forceinline__ float fast_rcp(float x)  { return __builtin_amdgcn_rcpf(x); }
__device__ __forceinline__ float fast_exp2(float x) { return __builtin_amdgcn_exp2f(x); }

#define C2F 2.88539008177792681f   // 2*log2(e)
#define L2E 1.44269504088896340f   // log2(e)

// ---------------------------------------------------------------------------
// Projection: P = in[rows x 256] @ W[256 x 64], out = exp2(C2F * P)
// ---------------------------------------------------------------------------
template<bool TRANSPOSED>
__global__ __launch_bounds__(256)
void proj_kernel(const float* __restrict__ in, const float* __restrict__ W,
                 float* __restrict__ out, const int* __restrict__ vlens,
                 int rowsPerB)
{
  const int t  = threadIdx.x;
  const int b  = blockIdx.x & 15;
  const int rt = blockIdx.x >> 4;
  const int r0 = rt * 64;
  if constexpr (TRANSPOSED) {
    if (r0 >= vlens[b]) return;
  }

  __shared__ float4 Wlds[256 * 16];   // [d][h-quad]
  __shared__ float  klds[64 * 36];

  const float4* W4 = (const float4*)W;
  #pragma unroll
  for (int i = 0; i < 16; ++i) Wlds[t + 256 * i] = W4[t + 256 * i];

  const float* inb = in + ((size_t)b * rowsPerB + r0) * 256;
  const int j = t >> 4;
  const int g = t & 15;

  float acc[4][4];
  #pragma unroll
  for (int m = 0; m < 4; ++m)
    acc[m][0] = acc[m][1] = acc[m][2] = acc[m][3] = 0.f;

  for (int dc = 0; dc < 8; ++dc) {
    {
      const int row = t >> 2, cs = (t & 3) * 8;
      const float* s = inb + row * 256 + dc * 32 + cs;
      float4 a0 = *(const float4*)s;
      float4 a1 = *(const float4*)(s + 4);
      float* dst = &klds[row * 36 + cs];
      *(float4*)dst       = a0;
      *(float4*)(dst + 4) = a1;
    }
    __syncthreads();
    #pragma unroll
    for (int d = 0; d < 32; ++d) {
      float4 w4 = Wlds[(dc * 32 + d) * 16 + j];
      #pragma unroll
      for (int m = 0; m < 4; ++m) {
        float kv = klds[(g + 16 * m) * 36 + d];
        acc[m][0] = fmaf(kv, w4.x, acc[m][0]);
        acc[m][1] = fmaf(kv, w4.y, acc[m][1]);
        acc[m][2] = fmaf(kv, w4.z, acc[m][2]);
        acc[m][3] = fmaf(kv, w4.w, acc[m][3]);
      }
    }
    __syncthreads();
  }

  if constexpr (TRANSPOSED) {
    #pragma unroll
    for (int m = 0; m < 4; ++m) {
      int k = r0 + g + 16 * m;
      size_t base = ((size_t)(b * 16 + (k >> 7)) * 64) * 128 + (k & 127);
      #pragma unroll
      for (int i = 0; i < 4; ++i)
        out[base + (size_t)(4 * j + i) * 128] = fast_exp2(C2F * acc[m][i]);
    }
  } else {
    #pragma unroll
    for (int m = 0; m < 4; ++m) {
      int row = r0 + g + 16 * m;
      float4 o;
      o.x = fast_exp2(C2F * acc[m][0]);
      o.y = fast_exp2(C2F * acc[m][1]);
      o.z = fast_exp2(C2F * acc[m][2]);
      o.w = fast_exp2(C2F * acc[m][3]);
      *(float4*)&out[((size_t)b * rowsPerB + row) * 64 + 4 * j] = o;
    }
  }
}

// ---------------------------------------------------------------------------
// Fused scores + exp + PV partial. Block = (b, 128-k tile, 16-q tile), 256 thr.
// ---------------------------------------------------------------------------
__global__ __launch_bounds__(256)
void scorepv_kernel(const float* __restrict__ Eq, const float* __restrict__ EkT,
                    const float* __restrict__ values, const int* __restrict__ vlens,
                    const float* __restrict__ wv,
                    float* __restrict__ partial, float* __restrict__ tsum)
{
  const int blk = blockIdx.x;          // b*128 + kt*8 + qq
  const int b   = blk >> 7;
  const int kt  = (blk >> 3) & 15;
  const int qq  = blk & 7;
  const int vl  = vlens[b];
  if (kt * 128 >= vl) return;

  __shared__ float ek_lds[64 * 128];   // 32KB; reused as p_lds[128][20] after barrier
  __shared__ float eq_lds[16 * 64];    // 4KB
  __shared__ float wv2_lds[64];

  const int t = threadIdx.x;

  float w0 = 0.f, W1 = 0.f;
  {
    const float4* wv4 = (const float4*)wv;
    #pragma unroll
    for (int u = 0; u < 16; ++u) {
      float4 v = wv4[u];
      w0 += v.x + v.y + v.z + v.w;
      W1 += fabsf(v.x) + fabsf(v.y) + fabsf(v.z) + fabsf(v.w);
    }
  }

  {
    const float4* src = (const float4*)(EkT + ((size_t)(b * 16 + kt) * 64) * 128);
    float4* dst = (float4*)ek_lds;
    #pragma unroll
    for (int i = 0; i < 8; ++i) dst[t + 256 * i] = src[t + 256 * i];
    const float4* qsrc = (const float4*)(Eq + (size_t)(b * 128 + qq * 16) * 64);
    ((float4*)eq_lds)[t] = qsrc[t];
    if (t < 64) wv2_lds[t] = -2.0f * wv[t];
  }
  __syncthreads();

  const int wave = t >> 6, lane = t & 63;
  const int q0l = wave * 4;            // wave's 4 q rows (exclusive)
  const int kp  = lane * 2;            // lane's k pair

  float s[4][2];
  #pragma unroll
  for (int q = 0; q < 4; ++q) { s[q][0] = w0; s[q][1] = w0; }

  #pragma unroll 4
  for (int h = 0; h < 64; ++h) {
    float2 ek = *(const float2*)&ek_lds[h * 128 + kp];
    float wvh = wv2_lds[h];
    #pragma unroll
    for (int q = 0; q < 4; ++q) {
      float eq = eq_lds[(q0l + q) * 64 + h];
      // paired reciprocal: 1 rcp serves 2 elements (rcp is quarter-rate)
      float x0 = fmaf(eq, ek.x, 1.0f);
      float x1 = fmaf(eq, ek.y, 1.0f);
      float r  = fast_rcp(x0 * x1);
      s[q][0] = fmaf(wvh, x1 * r, s[q][0]);
      s[q][1] = fmaf(wvh, x0 * r, s[q][1]);
    }
  }

  // p = exp2((s - W1)*L2E) in (0,1]; masked -> 0 (select, garbage-safe)
  const int kbase = kt * 128 + kp;
  float p[4][2];
  #pragma unroll
  for (int q = 0; q < 4; ++q) {
    p[q][0] = (kbase     < vl) ? fast_exp2((s[q][0] - W1) * L2E) : 0.f;
    p[q][1] = (kbase + 1 < vl) ? fast_exp2((s[q][1] - W1) * L2E) : 0.f;
  }

  // per-tile row sums (wave owns its q rows exclusively)
  #pragma unroll
  for (int q = 0; q < 4; ++q) {
    float e = p[q][0] + p[q][1];
    #pragma unroll
    for (int msk = 1; msk < 64; msk <<= 1) e += __shfl_xor(e, msk, 64);
    if (lane == 0)
      tsum[(size_t)(b * 16 + kt) * 128 + qq * 16 + q0l + q] = e;
  }

  __syncthreads();                     // all ek reads complete before reuse
  float* p_lds = ek_lds;               // [128 k][20 pad] (16B-aligned rows)
  #pragma unroll
  for (int q = 0; q < 4; ++q) {
    p_lds[kp * 20 + q0l + q]       = p[q][0];
    p_lds[(kp + 1) * 20 + q0l + q] = p[q][1];
  }
  __syncthreads();

  // PV: thread (qh, v); per k: 1 V dword (L2) + 2 float4 p broadcast + 8 fma
  const int v  = t & 127;
  const int qh = (t >> 7) * 8;
  const int kloc = min(128, vl - kt * 128);
  const float* vb = values + ((size_t)(b * 2048 + kt * 128)) * 128 + v;
  float acc[8] = {0.f, 0.f, 0.f, 0.f, 0.f, 0.f, 0.f, 0.f};
  #pragma unroll 4
  for (int k = 0; k < kloc; ++k) {
    float vx = vb[(size_t)k * 128];
    float4 pa = *(const float4*)&p_lds[k * 20 + qh];
    float4 pb = *(const float4*)&p_lds[k * 20 + qh + 4];
    acc[0] = fmaf(pa.x, vx, acc[0]); acc[1] = fmaf(pa.y, vx, acc[1]);
    acc[2] = fmaf(pa.z, vx, acc[2]); acc[3] = fmaf(pa.w, vx, acc[3]);
    acc[4] = fmaf(pb.x, vx, acc[4]); acc[5] = fmaf(pb.y, vx, acc[5]);
    acc[6] = fmaf(pb.z, vx, acc[6]); acc[7] = fmaf(pb.w, vx, acc[7]);
  }
  const int qg = qq * 16 + qh;
  #pragma unroll
  for (int i = 0; i < 8; ++i)
    partial[(((size_t)(b * 128 + qg + i)) * 16 + kt) * 128 + v] = acc[i];
}

// ---------------------------------------------------------------------------
// Reduce: out[b][q][v] = sum_kt partial / sum_kt tsum. Block = (b, 2-q), 256 thr.
// ---------------------------------------------------------------------------
__global__ __launch_bounds__(256)
void reduce_kernel(const float* __restrict__ partial, const float* __restrict__ tsum,
                   const int* __restrict__ vlens, float* __restrict__ out)
{
  const int blk = blockIdx.x;          // b*64 + qp
  const int b   = blk >> 6;
  const int q   = (blk & 63) * 2 + (threadIdx.x >> 7);
  const int v   = threadIdx.x & 127;
  const int ntk = (vlens[b] + 127) >> 7;

  float tot = 0.f;
  for (int i = 0; i < ntk; ++i)
    tot += tsum[(size_t)(b * 16 + i) * 128 + q];

  float acc = 0.f;
  const float* pp = partial + ((size_t)(b * 128 + q)) * 16 * 128 + v;
  for (int i = 0; i < ntk; ++i)
    acc += pp[(size_t)i * 128];

  out[((size_t)(b * 128 + q)) * 128 + v] = acc / tot;
}

// ---------------------------------------------------------------------------
// Fallback fused kernel (round-1, known-correct) for small ws_size.
// ---------------------------------------------------------------------------
__global__ __launch_bounds__(256)
void attn_kernel(const float* __restrict__ Eq, const float* __restrict__ EkT,
                 const float* __restrict__ values, const int* __restrict__ vlens,
                 const float* __restrict__ wv, float* __restrict__ out)
{
  const int t    = threadIdx.x;
  const int b    = blockIdx.x & 15;
  const int qt   = blockIdx.x >> 4;
  const int wave = t >> 6;
  const int lane = t & 63;

  __shared__ float4 sc4[512 * 4];
  __shared__ float  pvp[128 * 5];
  __shared__ float  linvs[4];

  const int vl = vlens[b];

  float eqv[64], wv2[64];
  float w0 = 0.f;
  {
    const float4* eq4 = (const float4*)(Eq + (size_t)(b * 128 + qt * 4 + wave) * 64);
    const float4* wv4 = (const float4*)wv;
    #pragma unroll
    for (int u = 0; u < 16; ++u) {
      float4 e = eq4[u], v = wv4[u];
      eqv[4*u+0] = e.x; eqv[4*u+1] = e.y; eqv[4*u+2] = e.z; eqv[4*u+3] = e.w;
      wv2[4*u+0] = -2.f * v.x; wv2[4*u+1] = -2.f * v.y;
      wv2[4*u+2] = -2.f * v.z; wv2[4*u+3] = -2.f * v.w;
      w0 += v.x + v.y + v.z + v.w;
    }
  }

  const int ktiles = (vl + 127) >> 7;
  const int kp = 2 * lane;
  for (int kt = 0; kt < ktiles; ++kt) {
    const float* tb = EkT + ((size_t)(b * 16 + kt) * 64) * 128 + kp;
    float s0 = w0, s1 = w0;
    #pragma unroll
    for (int h = 0; h < 64; ++h) {
      float2 ek = *(const float2*)(tb + (size_t)h * 128);
      float r0 = fast_rcp(fmaf(eqv[h], ek.x, 1.0f));
      float r1 = fast_rcp(fmaf(eqv[h], ek.y, 1.0f));
      s0 = fmaf(wv2[h], r0, s0);
      s1 = fmaf(wv2[h], r1, s1);
    }
    int k = kt * 128 + kp;
    if (k     >= vl) s0 = -1e9f;
    if (k + 1 >= vl) s1 = -1e9f;
    float* scf = (float*)sc4;
    *(float2*)(scf + (((k >> 2) * 4 + wave) * 4 + (k & 3))) = make_float2(s0, s1);
  }

  const int nq4 = (vl + 3) >> 2;
  float mx = -3e38f;
  for (int Q = lane; Q < nq4; Q += 64) {
    float4 f = sc4[Q * 4 + wave];
    mx = fmaxf(mx, fmaxf(fmaxf(f.x, f.y), fmaxf(f.z, f.w)));
  }
  #pragma unroll
  for (int msk = 1; msk < 64; msk <<= 1) mx = fmaxf(mx, __shfl_xor(mx, msk, 64));
  float lsum = 0.f;
  for (int Q = lane; Q < nq4; Q += 64) {
    float4 f = sc4[Q * 4 + wave];
    f.x = fast_exp2((f.x - mx) * L2E);
    f.y = fast_exp2((f.y - mx) * L2E);
    f.z = fast_exp2((f.z - mx) * L2E);
    f.w = fast_exp2((f.w - mx) * L2E);
    sc4[Q * 4 + wave] = f;
    lsum += f.x + f.y + f.z + f.w;
  }
  #pragma unroll
  for (int msk = 1; msk < 64; msk <<= 1) lsum += __shfl_xor(lsum, msk, 64);
  if (lane == 0) linvs[wave] = fast_rcp(lsum);
  __syncthreads();

  const int grp = t >> 7, v = t & 127;
  float acc[4] = {0.f, 0.f, 0.f, 0.f};
  const float* vb = values + (size_t)b * 2048 * 128 + v;
  for (int Q = grp; Q < nq4; Q += 2) {
    float4 p0 = sc4[Q * 4 + 0], p1 = sc4[Q * 4 + 1];
    float4 p2 = sc4[Q * 4 + 2], p3 = sc4[Q * 4 + 3];
    const float* vk = vb + (size_t)(Q * 4) * 128;
    float x;
    x = vk[0];
    acc[0]=fmaf(p0.x,x,acc[0]); acc[1]=fmaf(p1.x,x,acc[1]);
    acc[2]=fmaf(p2.x,x,acc[2]); acc[3]=fmaf(p3.x,x,acc[3]);
    x = vk[128];
    acc[0]=fmaf(p0.y,x,acc[0]); acc[1]=fmaf(p1.y,x,acc[1]);
    acc[2]=fmaf(p2.y,x,acc[2]); acc[3]=fmaf(p3.y,x,acc[3]);
    x = vk[256];
    acc[0]=fmaf(p0.z,x,acc[0]); acc[1]=fmaf(p1.z,x,acc[1]);
    acc[2]=fmaf(p2.z,x,acc[2]); acc[3]=fmaf(p3.z,x,acc[3]);
    x = vk[384];
    acc[0]=fmaf(p0.w,x,acc[0]); acc[1]=fmaf(p1.w,x,acc[1]);
    acc[2]=fmaf(p2.w,x,acc[2]); acc[3]=fmaf(p3.w,x,acc[3]);
  }
  if (grp == 1) {
    #pragma unroll
    for (int qq = 0; qq < 4; ++qq) pvp[v * 5 + qq] = acc[qq];
  }
  __syncthreads();
  if (grp == 0) {
    #pragma unroll
    for (int qq = 0; qq < 4; ++qq) {
      float tot = acc[qq] + pvp[v * 5 + qq];
      out[((size_t)(b * 128) + qt * 4 + qq) * 128 + v] = tot * linvs[qq];
    }
  }
}

// ---------------------------------------------------------------------------
extern "C" void kernel_launch(void* const* d_in, const int* in_sizes, int n_in,
                              void* d_out, int out_size, void* d_ws, size_t ws_size,
                              hipStream_t stream) {
  const float* queries = (const float*)d_in[0];   // [16][128][256]
  const float* keys    = (const float*)d_in[1];   // [16][2048][256]
  const float* values  = (const float*)d_in[2];   // [16][2048][128]
  const int*   vlens   = (const int*)d_in[3];     // [16]
  const float* Wq      = (const float*)d_in[4];   // [256][64]
  const float* Wk      = (const float*)d_in[5];   // [256][64]
  const float* wv      = (const float*)d_in[6];   // [64]
  float* outp = (float*)d_out;

  float* base    = (float*)d_ws;
  float* Eq      = base;                 // 131072 f
  float* EkT     = base + 131072;        // 2097152 f
  float* tsumb   = base + 2228224;       // 32768 f   [b][kt][q]
  float* partial = base + 2260992;       // 4194304 f [b][q][kt][v]
  const size_t need = (size_t)(2260992 + 4194304) * 4;

  hipLaunchKernelGGL((proj_kernel<false>), dim3(32),  dim3(256), 0, stream,
                     queries, Wq, Eq, (const int*)nullptr, 128);
  hipLaunchKernelGGL((proj_kernel<true>),  dim3(512), dim3(256), 0, stream,
                     keys, Wk, EkT, vlens, 2048);

  if (ws_size >= need) {
    hipLaunchKernelGGL(scorepv_kernel, dim3(2048), dim3(256), 0, stream,
                       Eq, EkT, values, vlens, wv, partial, tsumb);
    hipLaunchKernelGGL(reduce_kernel, dim3(1024), dim3(256), 0, stream,
                       partial, tsumb, vlens, outp);
  } else {
    hipLaunchKernelGGL(attn_kernel, dim3(512), dim3(256), 0, stream,
                       Eq, EkT, values, vlens, wv, outp);
  }
}